// Round 22
// baseline (245.354 us; speedup 1.0000x reference)
//
#include <hip/hip_runtime.h>

typedef unsigned int u32;
typedef unsigned long long u64;

#define NTOK 131072
#define DIMS 1024
#define NT   256

using bf16x8 = __attribute__((ext_vector_type(8))) short;
using f32x4  = __attribute__((ext_vector_type(4))) float;

// d_ws layout:
//   [0, 1MB)       Bf : bf16[2][32][64][16][8]; slice (p,ks)=16KB;
//                  within slice: L*128 + slot*8 shorts, slot = n ^ (L&15)
//   [1MB, +1KB)    Sv   : float[256] per-tile nonzero count (slow path)
//   [1MB+1KB)      flags: int[256]   per-tile "sig has exact zero"
//   [2MB, +33.5MB) pm   : u64[NTOK][32]; word ks of token T = p | (m<<32),
//                  bit b of p/m = (x[T][ks*32+b] >/< 0)
#define BF_OFF   0
#define SV_OFF   (1 << 20)
#define FLAG_OFF ((1 << 20) + 1024)
#define PM_OFF   (2 << 20)

// dist = Su + Sv - dot(a,b) - dot(u,v)  [R13-verified, exact]
// if sig has NO exact zeros: dist = 1024 - dot(a,b) exactly (any x).
__device__ __forceinline__ short sgnbf(float v) {
    return v > 0.f ? (short)0x3F80 : (v < 0.f ? (short)0xBF80 : (short)0);
}
__device__ __forceinline__ short absbf(float v) {
    return v != 0.f ? (short)0x3F80 : (short)0;
}

// ---------------------------------------------------------------------------
// Kernel A: B-fragments (bf16 sign/abs planes) in MFMA layout, slot-swizzled.
// (unchanged since R14 — bit-exact verified)
// ---------------------------------------------------------------------------
__global__ void sig_kernel(const float* __restrict__ base,
                           const float* __restrict__ deltas,
                           short* __restrict__ Bf,
                           float* __restrict__ Sv,
                           int* __restrict__ flags)
{
    const int t  = blockIdx.x;
    const int l  = threadIdx.x;
    const int ks = l >> 1;
    int nz = 0, zany = 0;
    #pragma unroll
    for (int gh = 0; gh < 2; ++gh) {
        const int g = (l & 1) * 2 + gh;
        bf16x8 a8, u8;
        #pragma unroll
        for (int j = 0; j < 8; ++j) {
            const int d  = ks * 32 + g * 8 + j;
            const float b  = base[d];
            const float dl = (t > 0) ? deltas[(size_t)(t - 1) * DIMS + d] : 0.f;
            const float s  = (dl != 0.f) ? dl : b;
            a8[j] = sgnbf(s);
            u8[j] = absbf(s);
            nz   += (s != 0.f) ? 1 : 0;
            zany |= (s == 0.f) ? 1 : 0;
        }
        const int L    = g * 16 + (t & 15);
        const int n    = t >> 4;
        const int slot = n ^ (t & 15);
        const size_t off = (size_t)L * 128 + slot * 8;
        *(bf16x8*)(Bf + (((size_t)0 * 32 + ks) << 13) + off) = a8;
        *(bf16x8*)(Bf + (((size_t)1 * 32 + ks) << 13) + off) = u8;
    }
    #pragma unroll
    for (int off = 1; off < 64; off <<= 1) nz += __shfl_xor(nz, off);
    const bool za = __any(zany != 0);
    if (l == 0) { Sv[t] = (float)nz; flags[t] = za ? 1 : 0; }
}

// ---------------------------------------------------------------------------
// Kernel B (pass 1): stream x -> ternary sign bit-planes. Copy-kernel shape:
// lane owns 32 consecutive dims of one token (8 chained float4 = 128B/lane
// in flight -> full MLP), packs p/m bits locally (no ballots/LDS/barriers),
// writes one u64 per (token, word). Wave writes 512B contiguous.
// ---------------------------------------------------------------------------
__global__ __launch_bounds__(256)
void xplanes_kernel(const float* __restrict__ x, u64* __restrict__ pm)
{
    const int lane = threadIdx.x & 63;
    const int w    = threadIdx.x >> 6;
    const int ks   = lane & 31;
    const int th   = lane >> 5;

    for (int bi = 0; bi < 8; ++bi) {
        const int T = blockIdx.x * 64 + bi * 8 + w * 2 + th;   // token
        const float* xr = x + (size_t)T * DIMS + ks * 32;
        u32 p = 0, m = 0;
        #pragma unroll
        for (int i = 0; i < 8; ++i) {
            const float4 v = *(const float4*)(xr + i * 4);
            p |= (((v.x > 0.f) ? 1u : 0u) << (4 * i))
               | (((v.y > 0.f) ? 1u : 0u) << (4 * i + 1))
               | (((v.z > 0.f) ? 1u : 0u) << (4 * i + 2))
               | (((v.w > 0.f) ? 1u : 0u) << (4 * i + 3));
            m |= (((v.x < 0.f) ? 1u : 0u) << (4 * i))
               | (((v.y < 0.f) ? 1u : 0u) << (4 * i + 1))
               | (((v.z < 0.f) ? 1u : 0u) << (4 * i + 2))
               | (((v.w < 0.f) ? 1u : 0u) << (4 * i + 3));
        }
        pm[(size_t)T * 32 + ks] = (u64)p | ((u64)m << 32);
    }
}

// ---------------------------------------------------------------------------
// Kernel C (pass 2): MFMA dist with ZERO x-traffic in the k-loop.
// R17-verified geometry: 4 waves, 128 tokens/block (32/wave, 2 m-frags),
// BK=32, B slices DMA'd (R16 STAGE, verified). A-fragments expanded from
// the block's pm bit-planes staged once in LDS (padded rows: token stride
// 33 u64 -> conflict-free b64 reads).
// R21 BUG FIX: bf16 expansion is ((p|m)*0x3F80) | (m<<15) — R21's
// p*0x3F80 | m<<15 gave -0.0 (0x8000) for negatives instead of -1.0
// (0xBF80), dropping all negative dot contributions.
// Fast: dist = 1024 - dot(a,b) (exact).
// Slow (sig zeros, ~never): second abs-plane pass, Su from bit popcounts.
// ---------------------------------------------------------------------------
__global__ __launch_bounds__(256, 2)
void dist_kernel(const u64* __restrict__ pm,
                 const short* __restrict__ Bf,
                 const float* __restrict__ Sv,
                 const int* __restrict__ flags,
                 float* __restrict__ idx_out,
                 float* __restrict__ dist_out)
{
    __shared__ short ldsb[2][8192];      // 32 KB: B slice double buffer
    __shared__ u64   ldm[128 * 33];      // 33.8 KB padded pm rows

    const int lane = threadIdx.x & 63;
    const int w    = threadIdx.x >> 6;
    const int tok0 = blockIdx.x * 128 + w * 32;
    const int mrow = lane & 15;
    const int g    = lane >> 4;

    const int ff = flags[lane] | flags[64 + lane] | flags[128 + lane] | flags[192 + lane];
    const bool sigz = __any(ff != 0);

    f32x4 acc0[16], acc1[16];
    #pragma unroll
    for (int n = 0; n < 16; ++n) {
        acc0[n] = (f32x4){0.f, 0.f, 0.f, 0.f};
        acc1[n] = (f32x4){0.f, 0.f, 0.f, 0.f};
    }

    // stage this block's pm words into LDS (pad 32->33 per token row)
    {
        const u64* src = pm + (size_t)blockIdx.x * 4096;
        #pragma unroll
        for (int k = 0; k < 16; ++k) {
            const int fw  = k * 256 + threadIdx.x;   // coalesced
            const int tok = fw >> 5, kk = fw & 31;
            ldm[tok * 33 + kk] = src[fw];
        }
    }

    // B DMA (R16-verified): wave w stages its 4KB quarter of slice (p,ks)
    auto STAGE = [&](int b, int p, int kss) {
        const short* src = Bf + (((size_t)p * 32 + kss) << 13) + w * 2048 + lane * 8;
        short* dst = &ldsb[b][w * 2048];
        #pragma unroll
        for (int i = 0; i < 4; ++i) {
            __builtin_amdgcn_global_load_lds(
                (const __attribute__((address_space(1))) u32*)(src + i * 512),
                (__attribute__((address_space(3))) u32*)(dst + i * 512),
                16, 0, 0);
        }
    };

    int nz0 = 0, nz1 = 0;
    const int nplanes = sigz ? 2 : 1;

    for (int p = 0; p < nplanes; ++p) {
        STAGE(0, p, 0);
        for (int ks = 0; ks < 32; ++ks) {
            __syncthreads();                       // slice (p,ks) DMA complete
            if (ks < 31) STAGE((ks + 1) & 1, p, ks + 1);

            // A-fragments from bit-planes
            const u64 pm0 = ldm[(w * 32 + mrow) * 33 + ks];
            const u64 pm1 = ldm[(w * 32 + 16 + mrow) * 33 + ks];
            const u32 pb0 = ((u32)pm0 >> (g * 8)) & 0xFF;
            const u32 mb0 = ((u32)(pm0 >> 32) >> (g * 8)) & 0xFF;
            const u32 pb1 = ((u32)pm1 >> (g * 8)) & 0xFF;
            const u32 mb1 = ((u32)(pm1 >> 32) >> (g * 8)) & 0xFF;

            bf16x8 f0, f1;
            if (p == 0) {
                const u32 ub0 = pb0 | mb0, ub1 = pb1 | mb1;
                #pragma unroll
                for (int j = 0; j < 8; ++j) {
                    f0[j] = (short)((((ub0 >> j) & 1u) * 0x3F80u) | (((mb0 >> j) & 1u) << 15));
                    f1[j] = (short)((((ub1 >> j) & 1u) * 0x3F80u) | (((mb1 >> j) & 1u) << 15));
                }
            } else {
                const u32 ub0 = pb0 | mb0, ub1 = pb1 | mb1;
                #pragma unroll
                for (int j = 0; j < 8; ++j) {
                    f0[j] = (short)(((ub0 >> j) & 1u) * 0x3F80u);
                    f1[j] = (short)(((ub1 >> j) & 1u) * 0x3F80u);
                }
                nz0 += __popc(ub0);
                nz1 += __popc(ub1);
            }

            const short* sb = &ldsb[ks & 1][0];
            __builtin_amdgcn_s_setprio(1);
            #pragma unroll
            for (int n = 0; n < 16; ++n) {
                const bf16x8 b = *(const bf16x8*)(sb + lane * 128 + ((n ^ mrow) & 15) * 8);
                acc0[n] = __builtin_amdgcn_mfma_f32_16x16x32_bf16(f0, b, acc0[n], 0, 0, 0);
                acc1[n] = __builtin_amdgcn_mfma_f32_16x16x32_bf16(f1, b, acc1[n], 0, 0, 0);
            }
            __builtin_amdgcn_s_setprio(0);
        }
        __syncthreads();                           // drain before plane restage
    }

    // ---- epilogue (R14/R17-verified) ----
    float su0r[4], su1r[4];
    if (sigz) {
        nz0 += __shfl_xor(nz0, 16); nz0 += __shfl_xor(nz0, 32);
        nz1 += __shfl_xor(nz1, 16); nz1 += __shfl_xor(nz1, 32);
        const float s0 = (float)nz0, s1 = (float)nz1;
        #pragma unroll
        for (int r = 0; r < 4; ++r) {
            su0r[r] = __shfl(s0, g * 4 + r);
            su1r[r] = __shfl(s1, g * 4 + r);
        }
    }

    int key0[4] = {0x7fffffff,0x7fffffff,0x7fffffff,0x7fffffff};
    int key1[4] = {0x7fffffff,0x7fffffff,0x7fffffff,0x7fffffff};
    #pragma unroll
    for (int n = 0; n < 16; ++n) {
        const int tile = n * 16 + mrow;
        const float svv = sigz ? Sv[tile] : 0.f;
        #pragma unroll
        for (int r = 0; r < 4; ++r) {
            const float dv0 = sigz ? (su0r[r] + svv - acc0[n][r]) : (1024.f - acc0[n][r]);
            const float dv1 = sigz ? (su1r[r] + svv - acc1[n][r]) : (1024.f - acc1[n][r]);
            dist_out[(size_t)(tok0 + g * 4 + r) * NT + tile]      = dv0;
            dist_out[(size_t)(tok0 + 16 + g * 4 + r) * NT + tile] = dv1;
            key0[r] = min(key0[r], ((int)dv0 << 8) | tile);
            key1[r] = min(key1[r], ((int)dv1 << 8) | tile);
        }
    }
    #pragma unroll
    for (int off = 1; off < 16; off <<= 1) {
        #pragma unroll
        for (int r = 0; r < 4; ++r) {
            key0[r] = min(key0[r], __shfl_xor(key0[r], off));
            key1[r] = min(key1[r], __shfl_xor(key1[r], off));
        }
    }
    if (mrow == 0) {
        #pragma unroll
        for (int r = 0; r < 4; ++r) {
            idx_out[tok0 + g * 4 + r]      = (float)(key0[r] & 255);
            idx_out[tok0 + 16 + g * 4 + r] = (float)(key1[r] & 255);
        }
    }
}

extern "C" void kernel_launch(void* const* d_in, const int* in_sizes, int n_in,
                              void* d_out, int out_size, void* d_ws, size_t ws_size,
                              hipStream_t stream)
{
    const float* x      = (const float*)d_in[0];
    const float* base   = (const float*)d_in[1];
    const float* deltas = (const float*)d_in[2];

    short* Bf    = (short*)((char*)d_ws + BF_OFF);
    float* Sv    = (float*)((char*)d_ws + SV_OFF);
    int*   flags = (int*)((char*)d_ws + FLAG_OFF);
    u64*   pm    = (u64*)((char*)d_ws + PM_OFF);

    float* idx_out  = (float*)d_out;                 // N floats (tile indices)
    float* dist_out = idx_out + NTOK;                // N*T floats

    sig_kernel<<<NT, 64, 0, stream>>>(base, deltas, Bf, Sv, flags);
    xplanes_kernel<<<NTOK / 64, 256, 0, stream>>>(x, pm);
    dist_kernel<<<NTOK / 128, 256, 0, stream>>>(pm, Bf, Sv, flags, idx_out, dist_out);
}

// Round 23
// 188.680 us; speedup vs baseline: 1.3004x; 1.3004x over previous
//
#include <hip/hip_runtime.h>

typedef unsigned int u32;

#define NTOK 131072
#define DIMS 1024
#define NT   256

using bf16x8 = __attribute__((ext_vector_type(8))) short;
using f32x4  = __attribute__((ext_vector_type(4))) float;

// d_ws layout:
//   [0, 1MB)        Bf : bf16[2][32][64][16][8]; slice (p,ks) = 16KB;
//                   within slice: L*128 + slot*8 shorts, slot = n ^ (L&15)
//   [1MB, +1KB)     Sv : float[256]   per-tile nonzero count (slow path)
//   [1MB+1KB, ..)   flags : int[256]  per-tile "sig has exact zero" flag
#define BF_OFF   0
#define SV_OFF   (1 << 20)
#define FLAG_OFF ((1 << 20) + 1024)

// dist = Su + Sv - dot(a,b) - dot(u,v)  [R13-verified, exact]
// if sig has NO exact zeros: dist = 1024 - dot(a,b) exactly (any x).
__device__ __forceinline__ short sgnbf(float v) {
    return v > 0.f ? (short)0x3F80 : (v < 0.f ? (short)0xBF80 : (short)0);
}
__device__ __forceinline__ short absbf(float v) {
    return v != 0.f ? (short)0x3F80 : (short)0;
}

// ---------------------------------------------------------------------------
// Kernel A: B-fragments (bf16 sign/abs planes) in MFMA layout, slot-swizzled.
// (unchanged since R14 — bit-exact verified)
// ---------------------------------------------------------------------------
__global__ void sig_kernel(const float* __restrict__ base,
                           const float* __restrict__ deltas,
                           short* __restrict__ Bf,
                           float* __restrict__ Sv,
                           int* __restrict__ flags)
{
    const int t  = blockIdx.x;
    const int l  = threadIdx.x;
    const int ks = l >> 1;
    int nz = 0, zany = 0;
    #pragma unroll
    for (int gh = 0; gh < 2; ++gh) {
        const int g = (l & 1) * 2 + gh;
        bf16x8 a8, u8;
        #pragma unroll
        for (int j = 0; j < 8; ++j) {
            const int d  = ks * 32 + g * 8 + j;
            const float b  = base[d];
            const float dl = (t > 0) ? deltas[(size_t)(t - 1) * DIMS + d] : 0.f;
            const float s  = (dl != 0.f) ? dl : b;
            a8[j] = sgnbf(s);
            u8[j] = absbf(s);
            nz   += (s != 0.f) ? 1 : 0;
            zany |= (s == 0.f) ? 1 : 0;
        }
        const int L    = g * 16 + (t & 15);
        const int n    = t >> 4;
        const int slot = n ^ (t & 15);
        const size_t off = (size_t)L * 128 + slot * 8;
        *(bf16x8*)(Bf + (((size_t)0 * 32 + ks) << 13) + off) = a8;
        *(bf16x8*)(Bf + (((size_t)1 * 32 + ks) << 13) + off) = u8;
    }
    #pragma unroll
    for (int off = 1; off < 64; off <<= 1) nz += __shfl_xor(nz, off);
    const bool za = __any(zany != 0);
    if (l == 0) { Sv[t] = (float)nz; flags[t] = za ? 1 : 0; }
}

// ---------------------------------------------------------------------------
// Kernel B: MFMA dist. 256 thr = 4 waves; block = 128 tokens (32/wave,
// 2-m-frag geometry, bit-exact since R13) x 256 tiles. BK=64: per phase kb,
// a 2-slice (32KB) buffer is staged via global_load_lds DMA while the
// current buffer feeds 32 ds_read_b128 + 64 MFMA per wave; x prefetched
// 1 phase ahead. 16 barriers. LDS 64KB -> 2 blocks/CU; regs fit (256,2).
// Session optimum (R17 = 189.5us): occupancy 2x (R16), counted vmcnt (R18),
// producer/consumer (R19), barrier-free fp8 (R20), split passes (R21/22)
// all measured null-to-negative vs this structure.
// Slow path (sig has exact zero, ~never): second plane pass, same acc.
// ---------------------------------------------------------------------------
__global__ __launch_bounds__(256, 2)
void dist_kernel(const float* __restrict__ x,
                 const short* __restrict__ Bf,
                 const float* __restrict__ Sv,
                 const int* __restrict__ flags,
                 float* __restrict__ idx_out,
                 float* __restrict__ dist_out)
{
    __shared__ short lds[2][16384];   // 64 KB: [buf][2 slices of 16KB]

    const int lane = threadIdx.x & 63;
    const int w    = threadIdx.x >> 6;
    const int tok0 = blockIdx.x * 128 + w * 32;
    const int mrow = lane & 15;
    const int g    = lane >> 4;

    const int ff = flags[lane] | flags[64 + lane] | flags[128 + lane] | flags[192 + lane];
    const bool sigz = __any(ff != 0);

    const float* __restrict__ xr0 = x + (size_t)(tok0 + mrow) * DIMS + g * 8;
    const float* __restrict__ xr1 = x + (size_t)(tok0 + 16 + mrow) * DIMS + g * 8;

    f32x4 acc0[16], acc1[16];
    #pragma unroll
    for (int n = 0; n < 16; ++n) {
        acc0[n] = (f32x4){0.f, 0.f, 0.f, 0.f};
        acc1[n] = (f32x4){0.f, 0.f, 0.f, 0.f};
    }

    // DMA stage: wave w copies its quarter of both slices of phase kb
    auto STAGE = [&](int b, int p, int kb) {
        #pragma unroll
        for (int s = 0; s < 2; ++s) {
            const short* src = Bf + (((size_t)p * 32 + 2 * kb + s) << 13) + w * 2048 + lane * 8;
            #pragma unroll
            for (int i = 0; i < 4; ++i) {
                __builtin_amdgcn_global_load_lds(
                    (const __attribute__((address_space(1))) u32*)(src + i * 512),
                    (__attribute__((address_space(3))) u32*)(&lds[b][s * 8192 + w * 2048 + i * 512]),
                    16, 0, 0);
            }
        }
    };

    int nz0 = 0, nz1 = 0;
    const int nplanes = sigz ? 2 : 1;

    for (int p = 0; p < nplanes; ++p) {
        STAGE(0, p, 0);
        float4 xv[8];
        xv[0] = *(const float4*)(xr0);       xv[1] = *(const float4*)(xr0 + 4);
        xv[2] = *(const float4*)(xr0 + 32);  xv[3] = *(const float4*)(xr0 + 36);
        xv[4] = *(const float4*)(xr1);       xv[5] = *(const float4*)(xr1 + 4);
        xv[6] = *(const float4*)(xr1 + 32);  xv[7] = *(const float4*)(xr1 + 36);

        for (int kb = 0; kb < 16; ++kb) {
            __syncthreads();   // buffer (p,kb) DMA + x(kb) loads complete

            float4 nx[8];
            if (kb < 15) {
                STAGE((kb + 1) & 1, p, kb + 1);
                const int o = (kb + 1) * 64;
                nx[0] = *(const float4*)(xr0 + o);      nx[1] = *(const float4*)(xr0 + o + 4);
                nx[2] = *(const float4*)(xr0 + o + 32); nx[3] = *(const float4*)(xr0 + o + 36);
                nx[4] = *(const float4*)(xr1 + o);      nx[5] = *(const float4*)(xr1 + o + 4);
                nx[6] = *(const float4*)(xr1 + o + 32); nx[7] = *(const float4*)(xr1 + o + 36);
            }

            if (p == 1) {
                #pragma unroll
                for (int i = 0; i < 4; ++i) {
                    nz0 += (xv[i][0]!=0.f)+(xv[i][1]!=0.f)+(xv[i][2]!=0.f)+(xv[i][3]!=0.f);
                    nz1 += (xv[4+i][0]!=0.f)+(xv[4+i][1]!=0.f)+(xv[4+i][2]!=0.f)+(xv[4+i][3]!=0.f);
                }
            }

            #pragma unroll
            for (int s = 0; s < 2; ++s) {
                const float4 a0 = xv[2 * s], a1 = xv[2 * s + 1];
                const float4 b0 = xv[4 + 2 * s], b1 = xv[4 + 2 * s + 1];
                bf16x8 f0, f1;
                if (p == 0) {
                    f0[0]=sgnbf(a0.x); f0[1]=sgnbf(a0.y); f0[2]=sgnbf(a0.z); f0[3]=sgnbf(a0.w);
                    f0[4]=sgnbf(a1.x); f0[5]=sgnbf(a1.y); f0[6]=sgnbf(a1.z); f0[7]=sgnbf(a1.w);
                    f1[0]=sgnbf(b0.x); f1[1]=sgnbf(b0.y); f1[2]=sgnbf(b0.z); f1[3]=sgnbf(b0.w);
                    f1[4]=sgnbf(b1.x); f1[5]=sgnbf(b1.y); f1[6]=sgnbf(b1.z); f1[7]=sgnbf(b1.w);
                } else {
                    f0[0]=absbf(a0.x); f0[1]=absbf(a0.y); f0[2]=absbf(a0.z); f0[3]=absbf(a0.w);
                    f0[4]=absbf(a1.x); f0[5]=absbf(a1.y); f0[6]=absbf(a1.z); f0[7]=absbf(a1.w);
                    f1[0]=absbf(b0.x); f1[1]=absbf(b0.y); f1[2]=absbf(b0.z); f1[3]=absbf(b0.w);
                    f1[4]=absbf(b1.x); f1[5]=absbf(b1.y); f1[6]=absbf(b1.z); f1[7]=absbf(b1.w);
                }

                const short* sa = &lds[kb & 1][s * 8192];
                __builtin_amdgcn_s_setprio(1);
                #pragma unroll
                for (int n = 0; n < 16; ++n) {
                    const bf16x8 ba = *(const bf16x8*)(sa + lane * 128 + ((n ^ mrow) & 15) * 8);
                    acc0[n] = __builtin_amdgcn_mfma_f32_16x16x32_bf16(f0, ba, acc0[n], 0, 0, 0);
                    acc1[n] = __builtin_amdgcn_mfma_f32_16x16x32_bf16(f1, ba, acc1[n], 0, 0, 0);
                }
                __builtin_amdgcn_s_setprio(0);
            }

            #pragma unroll
            for (int i = 0; i < 8; ++i) xv[i] = nx[i];
        }
        __syncthreads();   // both buffers drained before next plane restages
    }

    // ---- epilogue (R14-verified) ----
    float su0r[4], su1r[4];
    if (sigz) {
        nz0 += __shfl_xor(nz0, 16); nz0 += __shfl_xor(nz0, 32);
        nz1 += __shfl_xor(nz1, 16); nz1 += __shfl_xor(nz1, 32);
        const float s0 = (float)nz0, s1 = (float)nz1;
        #pragma unroll
        for (int r = 0; r < 4; ++r) {
            su0r[r] = __shfl(s0, g * 4 + r);
            su1r[r] = __shfl(s1, g * 4 + r);
        }
    }

    int key0[4] = {0x7fffffff,0x7fffffff,0x7fffffff,0x7fffffff};
    int key1[4] = {0x7fffffff,0x7fffffff,0x7fffffff,0x7fffffff};
    #pragma unroll
    for (int n = 0; n < 16; ++n) {
        const int tile = n * 16 + mrow;
        const float svv = sigz ? Sv[tile] : 0.f;
        #pragma unroll
        for (int r = 0; r < 4; ++r) {
            const float dv0 = sigz ? (su0r[r] + svv - acc0[n][r]) : (1024.f - acc0[n][r]);
            const float dv1 = sigz ? (su1r[r] + svv - acc1[n][r]) : (1024.f - acc1[n][r]);
            dist_out[(size_t)(tok0 + g * 4 + r) * NT + tile]      = dv0;
            dist_out[(size_t)(tok0 + 16 + g * 4 + r) * NT + tile] = dv1;
            key0[r] = min(key0[r], ((int)dv0 << 8) | tile);
            key1[r] = min(key1[r], ((int)dv1 << 8) | tile);
        }
    }
    #pragma unroll
    for (int off = 1; off < 16; off <<= 1) {
        #pragma unroll
        for (int r = 0; r < 4; ++r) {
            key0[r] = min(key0[r], __shfl_xor(key0[r], off));
            key1[r] = min(key1[r], __shfl_xor(key1[r], off));
        }
    }
    if (mrow == 0) {
        #pragma unroll
        for (int r = 0; r < 4; ++r) {
            idx_out[tok0 + g * 4 + r]      = (float)(key0[r] & 255);
            idx_out[tok0 + 16 + g * 4 + r] = (float)(key1[r] & 255);
        }
    }
}

extern "C" void kernel_launch(void* const* d_in, const int* in_sizes, int n_in,
                              void* d_out, int out_size, void* d_ws, size_t ws_size,
                              hipStream_t stream)
{
    const float* x      = (const float*)d_in[0];
    const float* base   = (const float*)d_in[1];
    const float* deltas = (const float*)d_in[2];

    short* Bf  = (short*)((char*)d_ws + BF_OFF);
    float* Sv  = (float*)((char*)d_ws + SV_OFF);
    int* flags = (int*)((char*)d_ws + FLAG_OFF);

    float* idx_out  = (float*)d_out;                 // N floats (tile indices)
    float* dist_out = idx_out + NTOK;                // N*T floats

    sig_kernel<<<NT, 64, 0, stream>>>(base, deltas, Bf, Sv, flags);
    dist_kernel<<<NTOK / 128, 256, 0, stream>>>(x, Bf, Sv, flags, idx_out, dist_out);
}